// Round 4
// baseline (589.036 us; speedup 1.0000x reference)
//
#include <hip/hip_runtime.h>
#include <math.h>

#define N_NODES 100000
#define N_EDGES 3200000
#define D_NODE 22
#define HIDDEN 32

// scan geometry: 98 blocks * 1024 elements = 100352 >= N_NODES
#define SCAN_ELEMS 1024
#define SCAN_NB    98
#define N_PAD      (SCAN_NB * SCAN_ELEMS)

#define EDGE_NB    (N_EDGES / 256)   // 12500 exact

// MFMA staging geometry
#define XS_LD 104        // bf16 row stride: 208 B, 16B-aligned, 2-way-bank-free
#define W2_LD 40         // W2t row stride

typedef short bf8 __attribute__((ext_vector_type(8)));  // 8 bf16 (4 VGPR)
typedef float f4  __attribute__((ext_vector_type(4)));  // MFMA acc

__device__ __forceinline__ float softplus_f(float v) {
    return fmaxf(v, 0.0f) + log1pf(expf(-fabsf(v)));
}

// manual RNE float->bf16 (avoids header API differences)
__device__ __forceinline__ unsigned short f2bf(float f) {
    unsigned int u = __float_as_uint(f);
    unsigned int r = (u + 0x7fffu + ((u >> 16) & 1u)) >> 16;
    return (unsigned short)r;
}
__device__ __forceinline__ unsigned int pk2(float a, float b) {
    return (unsigned int)f2bf(a) | ((unsigned int)f2bf(b) << 16);
}

// ---- CSR build ------------------------------------------------------------

__global__ __launch_bounds__(256) void count_rank_kernel(
    const int* __restrict__ ei, int* __restrict__ counts,
    int* __restrict__ rank)
{
    int e = blockIdx.x * blockDim.x + threadIdx.x;
    if (e < N_EDGES) rank[e] = atomicAdd(&counts[ei[e]], 1);
}

__global__ __launch_bounds__(256) void scan_part(
    const int* __restrict__ counts, int* __restrict__ offsets,
    int* __restrict__ bsums)
{
    __shared__ int lds[256];
    const int tid = threadIdx.x;
    const int base = blockIdx.x * SCAN_ELEMS + tid * 4;

    int v0 = (base + 0 < N_NODES) ? counts[base + 0] : 0;
    int v1 = (base + 1 < N_NODES) ? counts[base + 1] : 0;
    int v2 = (base + 2 < N_NODES) ? counts[base + 2] : 0;
    int v3 = (base + 3 < N_NODES) ? counts[base + 3] : 0;
    const int s = v0 + v1 + v2 + v3;

    lds[tid] = s;
    __syncthreads();
    for (int off = 1; off < 256; off <<= 1) {
        int t = (tid >= off) ? lds[tid - off] : 0;
        __syncthreads();
        lds[tid] += t;
        __syncthreads();
    }
    const int excl = lds[tid] - s;

    offsets[base + 0] = excl;
    offsets[base + 1] = excl + v0;
    offsets[base + 2] = excl + v0 + v1;
    offsets[base + 3] = excl + v0 + v1 + v2;

    if (tid == 0) bsums[blockIdx.x] = lds[255];
}

__global__ __launch_bounds__(128) void scan_sums(int* __restrict__ bsums)
{
    __shared__ int lds[128];
    const int tid = threadIdx.x;
    int v = (tid < SCAN_NB) ? bsums[tid] : 0;
    lds[tid] = v;
    __syncthreads();
    for (int off = 1; off < 128; off <<= 1) {
        int t = (tid >= off) ? lds[tid - off] : 0;
        __syncthreads();
        lds[tid] += t;
        __syncthreads();
    }
    if (tid < SCAN_NB) bsums[tid] = lds[tid] - v;
}

__global__ __launch_bounds__(256) void scan_add(
    int* __restrict__ offsets, const int* __restrict__ bsums)
{
    const int add = bsums[blockIdx.x];
    const int base = blockIdx.x * SCAN_ELEMS + threadIdx.x * 4;
    offsets[base + 0] += add;
    offsets[base + 1] += add;
    offsets[base + 2] += add;
    offsets[base + 3] += add;
}

// fallback-path fill
__global__ __launch_bounds__(256) void fill_kernel(
    const int* __restrict__ ei, const int* __restrict__ offsets,
    const int* __restrict__ rank, int* __restrict__ edge_list)
{
    int e = blockIdx.x * blockDim.x + threadIdx.x;
    if (e < N_EDGES)
        edge_list[offsets[ei[e]] + rank[e]] = e;
}

// ---- weight prep: bf16-transposed W1 (segment-remapped) and W2 ------------
// Xs cols: [0..21]=xi, [24..45]=xj, [48..69]=ea, rest 0. w1t[n][kc] matches.
__global__ __launch_bounds__(256) void prep_weights(
    const float* __restrict__ W1, const float* __restrict__ W2,
    unsigned short* __restrict__ w1t, unsigned short* __restrict__ w2t)
{
    const int tid = threadIdx.x;
    for (int i = tid; i < 32 * XS_LD; i += 256) {
        int n = i / XS_LD, kc = i - n * XS_LD;
        int kk = -1;
        if (kc < 22) kk = kc;
        else if (kc >= 24 && kc < 46) kk = kc - 2;
        else if (kc >= 48 && kc < 70) kk = kc - 4;
        w1t[i] = (kk >= 0) ? f2bf(W1[kk * 32 + n]) : (unsigned short)0;
    }
    for (int i = tid; i < 32 * W2_LD; i += 256) {
        int n = i / W2_LD, kc = i - n * W2_LD;
        w2t[i] = (kc < 32) ? f2bf(W2[kc * 32 + n]) : (unsigned short)0;
    }
}

// stage one 22-float segment (+2 pad cols) as bf16 into LDS
__device__ __forceinline__ void store_seg22(unsigned short* dst,
                                            const float* __restrict__ s)
{
    uint4 a;
    a.x = pk2(s[0], s[1]);   a.y = pk2(s[2], s[3]);
    a.z = pk2(s[4], s[5]);   a.w = pk2(s[6], s[7]);
    *reinterpret_cast<uint4*>(dst) = a;
    uint4 b;
    b.x = pk2(s[8], s[9]);   b.y = pk2(s[10], s[11]);
    b.z = pk2(s[12], s[13]); b.w = pk2(s[14], s[15]);
    *reinterpret_cast<uint4*>(dst + 8) = b;
    uint2 c;
    c.x = pk2(s[16], s[17]); c.y = pk2(s[18], s[19]);
    *reinterpret_cast<uint2*>(dst + 16) = c;
    *reinterpret_cast<unsigned int*>(dst + 20) = pk2(s[20], s[21]);
    *reinterpret_cast<unsigned int*>(dst + 22) = 0u;   // 2 pad cols
}

// ---- pass 1: natural-order edge MLP via MFMA, scatter msg to CSR position
__global__ __launch_bounds__(256) void edge_msg_mfma(
    const float* __restrict__ x,
    const int*   __restrict__ ei,
    const float* __restrict__ ea,
    const int*   __restrict__ rank,
    const int*   __restrict__ offsets,
    const unsigned short* __restrict__ w1t,
    const unsigned short* __restrict__ w2t,
    const float* __restrict__ b1,
    const float* __restrict__ b2,
    unsigned short* __restrict__ csr_msg)   // [E][32] bf16 in CSR order
{
    __shared__ unsigned short Xs[256 * XS_LD];   // 53248 B
    __shared__ unsigned short W1s[32 * XS_LD];   //  6656 B
    __shared__ unsigned short W2s[32 * W2_LD];   //  2560 B

    const int tid = threadIdx.x;
    const int e = blockIdx.x * 256 + tid;

    // weights -> LDS
    for (int i = tid; i < 32 * XS_LD / 2; i += 256)
        reinterpret_cast<unsigned int*>(W1s)[i] =
            reinterpret_cast<const unsigned int*>(w1t)[i];
    for (int i = tid; i < 32 * W2_LD / 2; i += 256)
        reinterpret_cast<unsigned int*>(W2s)[i] =
            reinterpret_cast<const unsigned int*>(w2t)[i];

    const int src = ei[e];
    const int dst = ei[N_EDGES + e];
    const int pos = offsets[src] + rank[e];     // unique CSR slot

    {
        unsigned short* row = Xs + tid * XS_LD;
        store_seg22(row + 0,  x + (size_t)src * D_NODE);
        store_seg22(row + 24, x + (size_t)dst * D_NODE);
        store_seg22(row + 48, ea + (size_t)e * D_NODE);
        uint4 z; z.x = z.y = z.z = z.w = 0u;
        *reinterpret_cast<uint4*>(row + 72) = z;
        *reinterpret_cast<uint4*>(row + 80) = z;
        *reinterpret_cast<uint4*>(row + 88) = z;   // cols 96..103 never read
    }
    __syncthreads();

    const int wv   = tid >> 6;
    const int lane = tid & 63;
    const int l16  = lane & 15;
    const int kq   = lane >> 4;       // 0..3
    const int rowbase = wv * 64;      // wave-private 64 rows of Xs

    // GEMM1: hid[256][32] = Xs[256][96] @ W1 (+b1 via C-init)
    f4 acc[4][2];
    {
        const float b1v0 = b1[l16];
        const float b1v1 = b1[l16 + 16];
#pragma unroll
        for (int mi = 0; mi < 4; ++mi) {
            acc[mi][0] = (f4){b1v0, b1v0, b1v0, b1v0};
            acc[mi][1] = (f4){b1v1, b1v1, b1v1, b1v1};
        }
    }
#pragma unroll
    for (int st = 0; st < 3; ++st) {
        const int kb = st * 32 + kq * 8;
        const bf8 bw0 = *reinterpret_cast<const bf8*>(W1s + l16 * XS_LD + kb);
        const bf8 bw1 = *reinterpret_cast<const bf8*>(W1s + (l16 + 16) * XS_LD + kb);
#pragma unroll
        for (int mi = 0; mi < 4; ++mi) {
            const bf8 af = *reinterpret_cast<const bf8*>(
                Xs + (rowbase + mi * 16 + l16) * XS_LD + kb);
            acc[mi][0] = __builtin_amdgcn_mfma_f32_16x16x32_bf16(af, bw0, acc[mi][0], 0, 0, 0);
            acc[mi][1] = __builtin_amdgcn_mfma_f32_16x16x32_bf16(af, bw1, acc[mi][1], 0, 0, 0);
        }
    }

    // ReLU -> bf16 hid written into Xs cols 0..31 (wave-private rows;
    // same-wave LDS ops are serviced in order, all GEMM1 reads precede)
#pragma unroll
    for (int mi = 0; mi < 4; ++mi)
#pragma unroll
    for (int ni = 0; ni < 2; ++ni)
#pragma unroll
    for (int r = 0; r < 4; ++r)
        Xs[(rowbase + mi * 16 + kq * 4 + r) * XS_LD + ni * 16 + l16] =
            f2bf(fmaxf(acc[mi][ni][r], 0.0f));

    // GEMM2: msg = hid @ W2 (+b2 via C-init)
    f4 acc2[4][2];
    {
        const float b2v0 = b2[l16];
        const float b2v1 = b2[l16 + 16];
#pragma unroll
        for (int mi = 0; mi < 4; ++mi) {
            acc2[mi][0] = (f4){b2v0, b2v0, b2v0, b2v0};
            acc2[mi][1] = (f4){b2v1, b2v1, b2v1, b2v1};
        }
    }
    {
        const bf8 cw0 = *reinterpret_cast<const bf8*>(W2s + l16 * W2_LD + kq * 8);
        const bf8 cw1 = *reinterpret_cast<const bf8*>(W2s + (l16 + 16) * W2_LD + kq * 8);
#pragma unroll
        for (int mi = 0; mi < 4; ++mi) {
            const bf8 hf = *reinterpret_cast<const bf8*>(
                Xs + (rowbase + mi * 16 + l16) * XS_LD + kq * 8);
            acc2[mi][0] = __builtin_amdgcn_mfma_f32_16x16x32_bf16(hf, cw0, acc2[mi][0], 0, 0, 0);
            acc2[mi][1] = __builtin_amdgcn_mfma_f32_16x16x32_bf16(hf, cw1, acc2[mi][1], 0, 0, 0);
        }
    }

    // msg -> bf16 back into Xs cols 0..31 (reads of hid all issued already)
#pragma unroll
    for (int mi = 0; mi < 4; ++mi)
#pragma unroll
    for (int ni = 0; ni < 2; ++ni)
#pragma unroll
    for (int r = 0; r < 4; ++r)
        Xs[(rowbase + mi * 16 + kq * 4 + r) * XS_LD + ni * 16 + l16] =
            f2bf(acc2[mi][ni][r]);

    // coalesced-in-LDS readback of own row, 64B scatter to CSR slot
    const uint4* mrow = reinterpret_cast<const uint4*>(Xs + tid * XS_LD);
    uint4 q0 = mrow[0], q1 = mrow[1], q2 = mrow[2], q3 = mrow[3];
    uint4* dstp = reinterpret_cast<uint4*>(csr_msg + (size_t)pos * 32);
    dstp[0] = q0; dstp[1] = q1; dstp[2] = q2; dstp[3] = q3;
}

// ---- pass 2: coalesced segmented reduction over CSR-ordered msgs ----------
__global__ __launch_bounds__(256) void reduce_kernel(
    const unsigned short* __restrict__ csr_msg,
    const int* __restrict__ offsets,
    float* __restrict__ agg)
{
    __shared__ float lmsg[256][33];
    __shared__ int   lsrc[256];
    __shared__ int   lstart[257];
    __shared__ unsigned long long lmask[4];

    const int tid = threadIdx.x;
    const int p = blockIdx.x * 256 + tid;

    const uint4* mr = reinterpret_cast<const uint4*>(csr_msg + (size_t)p * 32);
    uint4 m0 = mr[0], m1 = mr[1], m2 = mr[2], m3 = mr[3];
    unsigned int ww[16] = {m0.x, m0.y, m0.z, m0.w, m1.x, m1.y, m1.z, m1.w,
                           m2.x, m2.y, m2.z, m2.w, m3.x, m3.y, m3.z, m3.w};
#pragma unroll
    for (int d = 0; d < 16; ++d) {
        lmsg[tid][2 * d]     = __uint_as_float(ww[d] << 16);
        lmsg[tid][2 * d + 1] = __uint_as_float(ww[d] & 0xffff0000u);
    }

    // node owning position p: largest n with offsets[n] <= p
    int lo = 0, hi = N_NODES;
    while (hi - lo > 1) {
        int mid = (lo + hi) >> 1;
        if (offsets[mid] <= p) lo = mid; else hi = mid;
    }
    lsrc[tid] = lo;
    __syncthreads();

    const bool head = (tid == 0) || (lsrc[tid] != lsrc[tid - 1]);
    const unsigned long long m = __ballot(head ? 1 : 0);
    const int wv = tid >> 6, lane = tid & 63;
    if (lane == 0) lmask[wv] = m;
    __syncthreads();

    const int nseg = __popcll(lmask[0]) + __popcll(lmask[1]) +
                     __popcll(lmask[2]) + __popcll(lmask[3]);
    if (head) {
        int sid = 0;
        for (int w = 0; w < 4; ++w)
            if (w < wv) sid += __popcll(lmask[w]);
        const unsigned long long below =
            (lane == 0) ? 0ULL : (lmask[wv] & ((1ULL << lane) - 1ULL));
        sid += __popcll(below);
        lstart[sid] = tid;
    }
    if (tid == 0) lstart[nseg] = 256;
    __syncthreads();

    for (int item = tid; item < nseg * HIDDEN; item += 256) {
        const int s = item >> 5;
        const int c = item & 31;
        const int st = lstart[s];
        const int en = lstart[s + 1];
        float sum = 0.0f;
        for (int r = st; r < en; ++r) sum += lmsg[r][c];
        const int node = lsrc[st];
        float* dstp = agg + (size_t)node * HIDDEN + c;
        if (s == 0 || s == nseg - 1) atomicAdd(dstp, sum);
        else *dstp = sum;
    }
}

// ---- fallback: round-3 fused VALU kernel ----------------------------------
__global__ __launch_bounds__(256) void edge_mlp_reduce(
    const float* __restrict__ x,
    const int*   __restrict__ edge_index,
    const float* __restrict__ edge_attr,
    const int*   __restrict__ edge_list,
    const float* __restrict__ W1,
    const float* __restrict__ b1,
    const float* __restrict__ W2,
    const float* __restrict__ b2,
    float*       __restrict__ agg)
{
    __shared__ float lmsg[256][33];
    __shared__ int   lsrc[256];
    __shared__ int   lstart[257];
    __shared__ unsigned long long lmask[4];

    const int tid = threadIdx.x;
    const int p = blockIdx.x * 256 + tid;

    const int e   = edge_list[p];
    const int src = edge_index[e];
    const int j   = edge_index[N_EDGES + e];

    const float* __restrict__ xi = x + (size_t)src * D_NODE;
    const float* __restrict__ xj = x + (size_t)j   * D_NODE;
    const float* __restrict__ ep = edge_attr + (size_t)e * D_NODE;

    float hid[HIDDEN];
#pragma unroll
    for (int h = 0; h < HIDDEN; ++h) hid[h] = b1[h];
#pragma unroll
    for (int k = 0; k < D_NODE; ++k) {
        const float t = xi[k];
#pragma unroll
        for (int h = 0; h < HIDDEN; ++h)
            hid[h] = fmaf(t, W1[k * HIDDEN + h], hid[h]);
    }
#pragma unroll
    for (int k = 0; k < D_NODE; ++k) {
        const float t = xj[k];
#pragma unroll
        for (int h = 0; h < HIDDEN; ++h)
            hid[h] = fmaf(t, W1[(D_NODE + k) * HIDDEN + h], hid[h]);
    }
#pragma unroll
    for (int k = 0; k < D_NODE; ++k) {
        const float t = ep[k];
#pragma unroll
        for (int h = 0; h < HIDDEN; ++h)
            hid[h] = fmaf(t, W1[(2 * D_NODE + k) * HIDDEN + h], hid[h]);
    }
#pragma unroll
    for (int h = 0; h < HIDDEN; ++h) hid[h] = fmaxf(hid[h], 0.0f);

    float msg[HIDDEN];
#pragma unroll
    for (int o = 0; o < HIDDEN; ++o) msg[o] = b2[o];
#pragma unroll
    for (int k = 0; k < HIDDEN; ++k) {
        const float t = hid[k];
#pragma unroll
        for (int o = 0; o < HIDDEN; ++o)
            msg[o] = fmaf(t, W2[k * HIDDEN + o], msg[o]);
    }

    lsrc[tid] = src;
#pragma unroll
    for (int o = 0; o < HIDDEN; ++o) lmsg[tid][o] = msg[o];
    __syncthreads();

    const bool head = (tid == 0) || (lsrc[tid] != lsrc[tid - 1]);
    const unsigned long long m = __ballot(head ? 1 : 0);
    const int wv = tid >> 6, lane = tid & 63;
    if (lane == 0) lmask[wv] = m;
    __syncthreads();

    const int nseg = __popcll(lmask[0]) + __popcll(lmask[1]) +
                     __popcll(lmask[2]) + __popcll(lmask[3]);
    if (head) {
        int sid = 0;
        for (int w = 0; w < 4; ++w)
            if (w < wv) sid += __popcll(lmask[w]);
        const unsigned long long below =
            (lane == 0) ? 0ULL : (lmask[wv] & ((1ULL << lane) - 1ULL));
        sid += __popcll(below);
        lstart[sid] = tid;
    }
    if (tid == 0) lstart[nseg] = 256;
    __syncthreads();

    for (int item = tid; item < nseg * HIDDEN; item += 256) {
        const int s = item >> 5;
        const int c = item & 31;
        const int st = lstart[s];
        const int en = lstart[s + 1];
        float sum = 0.0f;
        for (int r = st; r < en; ++r) sum += lmsg[r][c];
        const int node = lsrc[st];
        float* dstp = agg + (size_t)node * HIDDEN + c;
        if (s == 0 || s == nseg - 1) atomicAdd(dstp, sum);
        else *dstp = sum;
    }
}

// ---- heads ---------------------------------------------------------------
__global__ __launch_bounds__(256) void node_head_kernel(
    const float* __restrict__ x,
    const float* __restrict__ agg,
    const float* __restrict__ Wmu,  const float* __restrict__ bmu,
    const float* __restrict__ Wsig, const float* __restrict__ bsig,
    const float* __restrict__ Wconc,const float* __restrict__ bconc,
    float*       __restrict__ out)
{
    int n = blockIdx.x * blockDim.x + threadIdx.x;
    if (n >= N_NODES) return;

    float mu = bmu[0], sg = bsig[0], al = bconc[0];

    const float* __restrict__ xp = x + (size_t)n * D_NODE;
#pragma unroll
    for (int k = 0; k < D_NODE; ++k) {
        const float t = xp[k];
        mu = fmaf(t, Wmu[k],   mu);
        sg = fmaf(t, Wsig[k],  sg);
        al = fmaf(t, Wconc[k], al);
    }
    const float* __restrict__ ap = agg + (size_t)n * HIDDEN;
#pragma unroll
    for (int k = 0; k < HIDDEN; ++k) {
        const float t = ap[k];
        mu = fmaf(t, Wmu[D_NODE + k],   mu);
        sg = fmaf(t, Wsig[D_NODE + k],  sg);
        al = fmaf(t, Wconc[D_NODE + k], al);
    }

    out[n]               = softplus_f(mu);
    out[N_NODES + n]     = softplus_f(sg);
    out[2 * N_NODES + n] = softplus_f(al);
}

// ---- launch ---------------------------------------------------------------

extern "C" void kernel_launch(void* const* d_in, const int* in_sizes, int n_in,
                              void* d_out, int out_size, void* d_ws, size_t ws_size,
                              hipStream_t stream) {
    const float* x     = (const float*)d_in[0];
    const int*   ei    = (const int*)  d_in[1];
    const float* ea    = (const float*)d_in[2];
    const float* W1    = (const float*)d_in[3];
    const float* b1    = (const float*)d_in[4];
    const float* W2    = (const float*)d_in[5];
    const float* b2    = (const float*)d_in[6];
    const float* Wmu   = (const float*)d_in[7];
    const float* bmu   = (const float*)d_in[8];
    const float* Wsig  = (const float*)d_in[9];
    const float* bsig  = (const float*)d_in[10];
    const float* Wconc = (const float*)d_in[11];
    const float* bconc = (const float*)d_in[12];

    float* out = (float*)d_out;

    // two-pass layout (dwords):
    // counts[N_PAD] | offsets[N_PAD] | bsums[128] | rank[E] | agg[N*32] |
    // w1t[32*104 bf16] | w2t[32*40 bf16] | csr_msg[E*32 bf16]
    int* counts  = (int*)d_ws;
    int* offsets = counts + N_PAD;
    int* bsums   = offsets + N_PAD;
    int* rank    = bsums + 128;
    float* agg   = (float*)(rank + N_EDGES);
    unsigned short* w1t = (unsigned short*)(agg + (size_t)N_NODES * HIDDEN);
    unsigned short* w2t = w1t + 32 * XS_LD;
    unsigned short* csr_msg = w2t + 32 * W2_LD;

    const size_t req =
        ((size_t)N_PAD * 2 + 128 + N_EDGES + (size_t)N_NODES * HIDDEN) * 4
        + (size_t)(32 * XS_LD + 32 * W2_LD) * 2
        + (size_t)N_EDGES * HIDDEN * 2;

    if (ws_size >= req) {
        hipMemsetAsync(counts, 0, N_PAD * sizeof(int), stream);
        prep_weights<<<1, 256, 0, stream>>>(W1, W2, w1t, w2t);
        count_rank_kernel<<<EDGE_NB, 256, 0, stream>>>(ei, counts, rank);
        scan_part<<<SCAN_NB, 256, 0, stream>>>(counts, offsets, bsums);
        scan_sums<<<1, 128, 0, stream>>>(bsums);
        scan_add<<<SCAN_NB, 256, 0, stream>>>(offsets, bsums);

        edge_msg_mfma<<<EDGE_NB, 256, 0, stream>>>(
            x, ei, ea, rank, offsets, w1t, w2t, b1, b2, csr_msg);

        hipMemsetAsync(agg, 0, (size_t)N_NODES * HIDDEN * sizeof(float), stream);
        reduce_kernel<<<EDGE_NB, 256, 0, stream>>>(csr_msg, offsets, agg);

        node_head_kernel<<<(N_NODES + 255) / 256, 256, 0, stream>>>(
            x, agg, Wmu, bmu, Wsig, bsig, Wconc, bconc, out);
    } else {
        // fallback: round-3 path (ws too small for csr_msg)
        int* edge_list = bsums + 128;
        int* rank_fb   = edge_list + N_EDGES;
        float* agg_fb  = (float*)rank_fb;

        hipMemsetAsync(counts, 0, N_PAD * sizeof(int), stream);
        count_rank_kernel<<<EDGE_NB, 256, 0, stream>>>(ei, counts, rank_fb);
        scan_part<<<SCAN_NB, 256, 0, stream>>>(counts, offsets, bsums);
        scan_sums<<<1, 128, 0, stream>>>(bsums);
        scan_add<<<SCAN_NB, 256, 0, stream>>>(offsets, bsums);
        fill_kernel<<<EDGE_NB, 256, 0, stream>>>(ei, offsets, rank_fb, edge_list);
        hipMemsetAsync(agg_fb, 0, (size_t)N_NODES * HIDDEN * sizeof(float), stream);
        edge_mlp_reduce<<<EDGE_NB, 256, 0, stream>>>(
            x, ei, ea, edge_list, W1, b1, W2, b2, agg_fb);
        node_head_kernel<<<(N_NODES + 255) / 256, 256, 0, stream>>>(
            x, agg_fb, Wmu, bmu, Wsig, bsig, Wconc, bconc, out);
    }
}